// Round 1
// baseline (459.434 us; speedup 1.0000x reference)
//
#include <hip/hip_runtime.h>
#include <cstdint>

#define NTOK 8192
#define DMODEL 1024
#define HDDIM 4096
#define NVEC 32

typedef float f32x4_v __attribute__((ext_vector_type(4)));
typedef __bf16 bf16x8 __attribute__((ext_vector_type(8)));
typedef unsigned short u16x4 __attribute__((ext_vector_type(4)));

__device__ __forceinline__ unsigned short f2bf(float f) {
  union { float f; uint32_t u; } x; x.f = f;
  uint32_t r = (x.u + 0x7FFFu + ((x.u >> 16) & 1u)) >> 16;
  return (unsigned short)r;
}

__device__ __forceinline__ float gelu_erf(float x) {
  return 0.5f * x * (1.0f + erff(x * 0.70710678118654752f));
}

// ---------------------------------------------------------------------------
// Reconstruct + transpose: outT[y][x] (bf16, ld=X) = sum_v c[v]*basis[v][x][y]
// basis rows (x) have Y contiguous elements. Memory-bound: streams X*Y*32 f32.
// Tile 64x * 64y per block, 256 threads.
// ---------------------------------------------------------------------------
__global__ __launch_bounds__(256)
void reconstruct_kernel(const float* __restrict__ basis,
                        const float* __restrict__ coeffs,
                        const int* __restrict__ eidx_p,
                        unsigned short* __restrict__ outT,
                        int X, int Y)
{
  const int e = *eidx_p;
  const int xtiles = X >> 6;
  const int bx = blockIdx.x % xtiles;
  const int by = blockIdx.x / xtiles;
  const int x0 = bx << 6, y0 = by << 6;
  const int t  = threadIdx.x;
  const int y4 = t & 15;   // y quad: y = y4*4 + j
  const int xg = t >> 4;   // 0..15:  x = xg*4 + i

  f32x4_v acc[4];
  #pragma unroll
  for (int i = 0; i < 4; ++i) acc[i] = (f32x4_v){0.f, 0.f, 0.f, 0.f};

  const size_t mat = (size_t)X * (size_t)Y;
  const float* base = basis + (size_t)(x0 + xg * 4) * Y + (y0 + y4 * 4);

  #pragma unroll 2
  for (int v = 0; v < NVEC; ++v) {
    const float cv = coeffs[e * NVEC + v];   // uniform, cached scalar load
    const float* pv = base + (size_t)v * mat;
    #pragma unroll
    for (int i = 0; i < 4; ++i) {
      f32x4_v d = *(const f32x4_v*)(pv + (size_t)i * Y);
      acc[i] += cv * d;
    }
  }

  // transpose via LDS (padded: stride-65 dwords -> conflict-free-ish)
  __shared__ float lds[64][65];
  #pragma unroll
  for (int i = 0; i < 4; ++i)
    #pragma unroll
    for (int j = 0; j < 4; ++j)
      lds[xg * 4 + i][y4 * 4 + j] = acc[i][j];
  __syncthreads();

  const int x4 = t & 15;
  const int yr = t >> 4;
  #pragma unroll
  for (int yy = 0; yy < 4; ++yy) {
    const int y = yr + yy * 16;
    u16x4 u;
    #pragma unroll
    for (int i = 0; i < 4; ++i) u[i] = f2bf(lds[x4 * 4 + i][y]);
    *(u16x4*)(outT + (size_t)(y0 + y) * X + x0 + x4 * 4) = u;
  }
}

// ---------------------------------------------------------------------------
// fp32 -> bf16 elementwise (inputs)
// ---------------------------------------------------------------------------
__global__ __launch_bounds__(256)
void cvt_f32_bf16(const float* __restrict__ in, unsigned short* __restrict__ out, int n4)
{
  const int i = blockIdx.x * 256 + threadIdx.x;
  if (i >= n4) return;
  f32x4_v v = ((const f32x4_v*)in)[i];
  u16x4 u;
  #pragma unroll
  for (int j = 0; j < 4; ++j) u[j] = f2bf(v[j]);
  ((u16x4*)out)[i] = u;
}

// ---------------------------------------------------------------------------
// GEMM (m97 structure): C[M,N] = A[M,K] * Bt[N,K]^T, bf16 in, fp32 acc.
// 128x128 tile, BK=64, 4 waves (2x2), 16x16x32 MFMA, global_load_lds w=16.
// EPI==0: C = gelu_erf(acc) -> bf16.  EPI==1: C = acc + bias[col] -> f32.
// ---------------------------------------------------------------------------
__device__ __forceinline__ void gload16(const unsigned short* g, unsigned short* lds)
{
  __builtin_amdgcn_global_load_lds((__attribute__((address_space(1))) void*)g,
                                   (__attribute__((address_space(3))) void*)lds,
                                   16, 0, 0);
}

template<int EPI>
__global__ __launch_bounds__(256)
void gemm_bt(const unsigned short* __restrict__ A,
             const unsigned short* __restrict__ Bt,
             unsigned short* __restrict__ Cbf,
             float* __restrict__ Cf,
             const float* __restrict__ bias,
             const int* __restrict__ eidx_p,
             int M, int N, int K)
{
  constexpr int BM = 128, BN = 128, BK = 64;
  __shared__ unsigned short sA[BM * BK];
  __shared__ unsigned short sB[BN * BK];

  const int nb = N / BN;
  const int bm = blockIdx.x / nb;
  const int bn = blockIdx.x % nb;
  const int m0 = bm * BM, n0 = bn * BN;

  const int t = threadIdx.x;
  const int w = t >> 6;
  const int l = t & 63;
  const int wm = w >> 1, wn = w & 1;

  f32x4_v acc[4][4];
  #pragma unroll
  for (int i = 0; i < 4; ++i)
    #pragma unroll
    for (int j = 0; j < 4; ++j) acc[i][j] = (f32x4_v){0.f, 0.f, 0.f, 0.f};

  const int trow = t >> 3;        // 0..31: tile row per stage-call
  const int tk   = (t & 7) * 8;   // bf16 k-offset within BK
  const unsigned short* a_src = A  + (size_t)(m0 + trow) * K + tk;
  const unsigned short* b_src = Bt + (size_t)(n0 + trow) * K + tk;

  const int lrow = l & 15;        // fragment row (A) / col (B)
  const int lk   = (l >> 4) * 8;  // fragment k-offset

  for (int kt = 0; kt < K; kt += BK) {
    #pragma unroll
    for (int c = 0; c < 4; ++c) {
      gload16(a_src + (size_t)(c * 32) * K + kt, sA + c * 2048 + w * 512);
      gload16(b_src + (size_t)(c * 32) * K + kt, sB + c * 2048 + w * 512);
    }
    __syncthreads();   // drains vmcnt -> tiles ready
    #pragma unroll
    for (int kk = 0; kk < 2; ++kk) {
      bf16x8 af[4], bfr[4];
      #pragma unroll
      for (int mi = 0; mi < 4; ++mi)
        af[mi] = *(const bf16x8*)(sA + (wm * 64 + mi * 16 + lrow) * BK + kk * 32 + lk);
      #pragma unroll
      for (int ni = 0; ni < 4; ++ni)
        bfr[ni] = *(const bf16x8*)(sB + (wn * 64 + ni * 16 + lrow) * BK + kk * 32 + lk);
      #pragma unroll
      for (int mi = 0; mi < 4; ++mi)
        #pragma unroll
        for (int ni = 0; ni < 4; ++ni)
          acc[mi][ni] = __builtin_amdgcn_mfma_f32_16x16x32_bf16(af[mi], bfr[ni], acc[mi][ni], 0, 0, 0);
    }
    __syncthreads();   // protect LDS before next stage
  }

  // Epilogue. C/D frag: col = lane&15, row = (lane>>4)*4 + reg  [m89/m91]
  const int colq = l & 15;
  const int rowq = (l >> 4) * 4;
  if (EPI == 0) {
    #pragma unroll
    for (int mi = 0; mi < 4; ++mi)
      #pragma unroll
      for (int ni = 0; ni < 4; ++ni) {
        const int col = n0 + wn * 64 + ni * 16 + colq;
        #pragma unroll
        for (int r = 0; r < 4; ++r) {
          const int row = m0 + wm * 64 + mi * 16 + rowq + r;
          Cbf[(size_t)row * N + col] = f2bf(gelu_erf(acc[mi][ni][r]));
        }
      }
  } else {
    const int e = *eidx_p;
    const float* brow = bias + (size_t)e * N;
    #pragma unroll
    for (int ni = 0; ni < 4; ++ni) {
      const int col = n0 + wn * 64 + ni * 16 + colq;
      const float bv = brow[col];
      #pragma unroll
      for (int mi = 0; mi < 4; ++mi)
        #pragma unroll
        for (int r = 0; r < 4; ++r) {
          const int row = m0 + wm * 64 + mi * 16 + rowq + r;
          Cf[(size_t)row * N + col] = acc[mi][ni][r] + bv;
        }
    }
  }
}

// ---------------------------------------------------------------------------
extern "C" void kernel_launch(void* const* d_in, const int* in_sizes, int n_in,
                              void* d_out, int out_size, void* d_ws, size_t ws_size,
                              hipStream_t stream)
{
  const float* inputs     = (const float*)d_in[0];
  const float* basis_up   = (const float*)d_in[1];
  const float* basis_down = (const float*)d_in[2];
  const float* cup        = (const float*)d_in[3];
  const float* cdn        = (const float*)d_in[4];
  const float* bias       = (const float*)d_in[5];
  const int*   eidx       = (const int*)d_in[6];
  float*       out        = (float*)d_out;

  char* ws = (char*)d_ws;
  unsigned short* A_bf   = (unsigned short*)(ws);                  // 16 MB
  unsigned short* WupT   = (unsigned short*)(ws + (16u << 20));    //  8 MB  [HDDIM][DMODEL]
  unsigned short* WdnT   = (unsigned short*)(ws + (24u << 20));    //  8 MB  [DMODEL][HDDIM]
  unsigned short* hidden = (unsigned short*)(ws + (32u << 20));    // 64 MB  [NTOK][HDDIM]

  // inputs -> bf16
  const int n4 = NTOK * DMODEL / 4;
  cvt_f32_bf16<<<(n4 + 255) / 256, 256, 0, stream>>>(inputs, A_bf, n4);

  // W_upT[h][d] = sum_v c[v]*basis_up[v][d][h]   (X=DMODEL rows, Y=HDDIM contig)
  reconstruct_kernel<<<(DMODEL / 64) * (HDDIM / 64), 256, 0, stream>>>(
      basis_up, cup, eidx, WupT, DMODEL, HDDIM);
  // W_downT[d][h] = sum_v c[v]*basis_down[v][h][d] (X=HDDIM rows, Y=DMODEL contig)
  reconstruct_kernel<<<(HDDIM / 64) * (DMODEL / 64), 256, 0, stream>>>(
      basis_down, cdn, eidx, WdnT, HDDIM, DMODEL);

  // hidden = gelu(inputs @ W_up)        M=8192 N=4096 K=1024
  gemm_bt<0><<<(NTOK / 128) * (HDDIM / 128), 256, 0, stream>>>(
      A_bf, WupT, hidden, nullptr, nullptr, nullptr, NTOK, HDDIM, DMODEL);

  // out = hidden @ W_down + bias        M=8192 N=1024 K=4096
  gemm_bt<1><<<(NTOK / 128) * (DMODEL / 128), 256, 0, stream>>>(
      hidden, WdnT, nullptr, out, bias, eidx, NTOK, DMODEL, HDDIM);
}

// Round 2
// 455.051 us; speedup vs baseline: 1.0096x; 1.0096x over previous
//
#include <hip/hip_runtime.h>
#include <cstdint>

#define NTOK 8192
#define DMODEL 1024
#define HDDIM 4096
#define NVEC 32

typedef float f32x4_v __attribute__((ext_vector_type(4)));
typedef __bf16 bf16x8 __attribute__((ext_vector_type(8)));
typedef unsigned short u16x4 __attribute__((ext_vector_type(4)));

__device__ __forceinline__ unsigned short f2bf(float f) {
  union { float f; uint32_t u; } x; x.f = f;
  uint32_t r = (x.u + 0x7FFFu + ((x.u >> 16) & 1u)) >> 16;
  return (unsigned short)r;
}

__device__ __forceinline__ float gelu_erf(float x) {
  return 0.5f * x * (1.0f + erff(x * 0.70710678118654752f));
}

// ---------------------------------------------------------------------------
// Reconstruct + transpose body: outT[y][x] (bf16, ld=X) = sum_v c[v]*basis[v][x][y]
// 64x * 64y tile per block, 256 threads, LDS transpose (stride-65 dwords).
// ---------------------------------------------------------------------------
__device__ __forceinline__
void reconstruct_body(const float* __restrict__ basis,
                      const float* __restrict__ coeffs,
                      int e, unsigned short* __restrict__ outT,
                      int X, int Y, int tile, char* smem)
{
  float (*lds)[65] = (float (*)[65])smem;
  const int xtiles = X >> 6;
  const int bx = tile % xtiles;
  const int by = tile / xtiles;
  const int x0 = bx << 6, y0 = by << 6;
  const int t  = threadIdx.x;
  const int y4 = t & 15;
  const int xg = t >> 4;

  f32x4_v acc[4];
  #pragma unroll
  for (int i = 0; i < 4; ++i) acc[i] = (f32x4_v){0.f, 0.f, 0.f, 0.f};

  const size_t mat = (size_t)X * (size_t)Y;
  const float* base = basis + (size_t)(x0 + xg * 4) * Y + (y0 + y4 * 4);

  #pragma unroll 2
  for (int v = 0; v < NVEC; ++v) {
    const float cv = coeffs[e * NVEC + v];
    const float* pv = base + (size_t)v * mat;
    #pragma unroll
    for (int i = 0; i < 4; ++i) {
      f32x4_v d = *(const f32x4_v*)(pv + (size_t)i * Y);
      acc[i] += cv * d;
    }
  }

  #pragma unroll
  for (int i = 0; i < 4; ++i)
    #pragma unroll
    for (int j = 0; j < 4; ++j)
      lds[xg * 4 + i][y4 * 4 + j] = acc[i][j];
  __syncthreads();

  const int x4 = t & 15;
  const int yr = t >> 4;
  #pragma unroll
  for (int yy = 0; yy < 4; ++yy) {
    const int y = yr + yy * 16;
    u16x4 u;
    #pragma unroll
    for (int i = 0; i < 4; ++i) u[i] = f2bf(lds[x4 * 4 + i][y]);
    *(u16x4*)(outT + (size_t)(y0 + y) * X + x0 + x4 * 4) = u;
  }
}

// ---------------------------------------------------------------------------
// GEMM body (m97 structure): C[M,N] = A[M,K] * Bt[N,K]^T, bf16 in, fp32 acc.
// 128x128 tile, BK=64, 4 waves (2x2), 16x16x32 MFMA, global_load_lds w=16.
// EPI==0: C = gelu_erf(acc) -> bf16.  EPI==1: C = acc + bias[col] -> f32.
// ---------------------------------------------------------------------------
__device__ __forceinline__ void gload16(const unsigned short* g, unsigned short* lds)
{
  __builtin_amdgcn_global_load_lds((__attribute__((address_space(1))) void*)g,
                                   (__attribute__((address_space(3))) void*)lds,
                                   16, 0, 0);
}

template<int EPI>
__device__ __forceinline__
void gemm_body(const unsigned short* __restrict__ A,
               const unsigned short* __restrict__ Bt,
               unsigned short* __restrict__ Cbf,
               float* __restrict__ Cf,
               const float* __restrict__ bias, int e,
               int M, int N, int K, int tile, char* smem)
{
  constexpr int BM = 128, BN = 128, BK = 64;
  unsigned short* sA = (unsigned short*)smem;          // 16 KB
  unsigned short* sB = (unsigned short*)(smem + 16384); // 16 KB

  const int nb = N / BN;
  const int bm = tile / nb;
  const int bn = tile % nb;
  const int m0 = bm * BM, n0 = bn * BN;

  const int t = threadIdx.x;
  const int w = t >> 6;
  const int l = t & 63;
  const int wm = w >> 1, wn = w & 1;

  f32x4_v acc[4][4];
  #pragma unroll
  for (int i = 0; i < 4; ++i)
    #pragma unroll
    for (int j = 0; j < 4; ++j) acc[i][j] = (f32x4_v){0.f, 0.f, 0.f, 0.f};

  const int trow = t >> 3;
  const int tk   = (t & 7) * 8;
  const unsigned short* a_src = A  + (size_t)(m0 + trow) * K + tk;
  const unsigned short* b_src = Bt + (size_t)(n0 + trow) * K + tk;

  const int lrow = l & 15;
  const int lk   = (l >> 4) * 8;

  for (int kt = 0; kt < K; kt += BK) {
    #pragma unroll
    for (int c = 0; c < 4; ++c) {
      gload16(a_src + (size_t)(c * 32) * K + kt, sA + c * 2048 + w * 512);
      gload16(b_src + (size_t)(c * 32) * K + kt, sB + c * 2048 + w * 512);
    }
    __syncthreads();
    #pragma unroll
    for (int kk = 0; kk < 2; ++kk) {
      bf16x8 af[4], bfr[4];
      #pragma unroll
      for (int mi = 0; mi < 4; ++mi)
        af[mi] = *(const bf16x8*)(sA + (wm * 64 + mi * 16 + lrow) * BK + kk * 32 + lk);
      #pragma unroll
      for (int ni = 0; ni < 4; ++ni)
        bfr[ni] = *(const bf16x8*)(sB + (wn * 64 + ni * 16 + lrow) * BK + kk * 32 + lk);
      #pragma unroll
      for (int mi = 0; mi < 4; ++mi)
        #pragma unroll
        for (int ni = 0; ni < 4; ++ni)
          acc[mi][ni] = __builtin_amdgcn_mfma_f32_16x16x32_bf16(af[mi], bfr[ni], acc[mi][ni], 0, 0, 0);
    }
    __syncthreads();
  }

  const int colq = l & 15;
  const int rowq = (l >> 4) * 4;
  if (EPI == 0) {
    #pragma unroll
    for (int mi = 0; mi < 4; ++mi)
      #pragma unroll
      for (int ni = 0; ni < 4; ++ni) {
        const int col = n0 + wn * 64 + ni * 16 + colq;
        #pragma unroll
        for (int r = 0; r < 4; ++r) {
          const int row = m0 + wm * 64 + mi * 16 + rowq + r;
          Cbf[(size_t)row * N + col] = f2bf(gelu_erf(acc[mi][ni][r]));
        }
      }
  } else {
    const float* brow = bias + (size_t)e * N;
    #pragma unroll
    for (int ni = 0; ni < 4; ++ni) {
      const int col = n0 + wn * 64 + ni * 16 + colq;
      const float bv = brow[col];
      #pragma unroll
      for (int mi = 0; mi < 4; ++mi)
        #pragma unroll
        for (int r = 0; r < 4; ++r) {
          const int row = m0 + wm * 64 + mi * 16 + rowq + r;
          Cf[(size_t)row * N + col] = acc[mi][ni][r] + bv;
        }
    }
  }
}

// ---------------------------------------------------------------------------
// Phase 1: rec_up (blocks 0..1023) + cvt f32->bf16 grid-stride (blocks 1024..1535)
// ---------------------------------------------------------------------------
#define REC_UP_BLKS 1024   // (DMODEL/64)*(HDDIM/64)
#define CVT_BLKS    512

__global__ __launch_bounds__(256)
void phase1_kernel(const float* __restrict__ inputs,
                   const float* __restrict__ basis_up,
                   const float* __restrict__ cup,
                   const int* __restrict__ eidx_p,
                   unsigned short* __restrict__ A_bf,
                   unsigned short* __restrict__ WupT)
{
  __shared__ __align__(16) char smem[32768];
  const int bid = blockIdx.x;
  if (bid < REC_UP_BLKS) {
    reconstruct_body(basis_up, cup, *eidx_p, WupT, DMODEL, HDDIM, bid, smem);
  } else {
    const int n4 = NTOK * DMODEL / 4;
    const int stride = CVT_BLKS * 256;
    for (int i = (bid - REC_UP_BLKS) * 256 + threadIdx.x; i < n4; i += stride) {
      f32x4_v v = ((const f32x4_v*)inputs)[i];
      u16x4 u;
      #pragma unroll
      for (int j = 0; j < 4; ++j) u[j] = f2bf(v[j]);
      ((u16x4*)A_bf)[i] = u;
    }
  }
}

// ---------------------------------------------------------------------------
// Phase 2: gemm1 (2048 tiles) interleaved 2:1 with rec_dn (1024 tiles)
// bid%3==2 -> rec tile bid/3 ; else gemm tile (bid/3)*2 + bid%3
// ---------------------------------------------------------------------------
__global__ __launch_bounds__(256)
void phase2_kernel(const unsigned short* __restrict__ A_bf,
                   const unsigned short* __restrict__ WupT,
                   unsigned short* __restrict__ hidden,
                   const float* __restrict__ basis_down,
                   const float* __restrict__ cdn,
                   const int* __restrict__ eidx_p,
                   unsigned short* __restrict__ WdnT)
{
  __shared__ __align__(16) char smem[32768];
  const int bid = blockIdx.x;
  const int r = bid % 3, q = bid / 3;
  if (r == 2) {
    reconstruct_body(basis_down, cdn, *eidx_p, WdnT, HDDIM, DMODEL, q, smem);
  } else {
    gemm_body<0>(A_bf, WupT, hidden, nullptr, nullptr, 0,
                 NTOK, HDDIM, DMODEL, q * 2 + r, smem);
  }
}

// ---------------------------------------------------------------------------
// Phase 3: gemm2
// ---------------------------------------------------------------------------
__global__ __launch_bounds__(256)
void phase3_kernel(const unsigned short* __restrict__ hidden,
                   const unsigned short* __restrict__ WdnT,
                   float* __restrict__ out,
                   const float* __restrict__ bias,
                   const int* __restrict__ eidx_p)
{
  __shared__ __align__(16) char smem[32768];
  gemm_body<1>(hidden, WdnT, nullptr, out, bias, *eidx_p,
               NTOK, DMODEL, HDDIM, blockIdx.x, smem);
}

// ---------------------------------------------------------------------------
extern "C" void kernel_launch(void* const* d_in, const int* in_sizes, int n_in,
                              void* d_out, int out_size, void* d_ws, size_t ws_size,
                              hipStream_t stream)
{
  const float* inputs     = (const float*)d_in[0];
  const float* basis_up   = (const float*)d_in[1];
  const float* basis_down = (const float*)d_in[2];
  const float* cup        = (const float*)d_in[3];
  const float* cdn        = (const float*)d_in[4];
  const float* bias       = (const float*)d_in[5];
  const int*   eidx       = (const int*)d_in[6];
  float*       out        = (float*)d_out;

  char* ws = (char*)d_ws;
  unsigned short* A_bf   = (unsigned short*)(ws);                  // 16 MB
  unsigned short* WupT   = (unsigned short*)(ws + (16u << 20));    //  8 MB  [HDDIM][DMODEL]
  unsigned short* WdnT   = (unsigned short*)(ws + (24u << 20));    //  8 MB  [DMODEL][HDDIM]
  unsigned short* hidden = (unsigned short*)(ws + (32u << 20));    // 64 MB  [NTOK][HDDIM]

  phase1_kernel<<<REC_UP_BLKS + CVT_BLKS, 256, 0, stream>>>(
      inputs, basis_up, cup, eidx, A_bf, WupT);

  phase2_kernel<<<3072, 256, 0, stream>>>(
      A_bf, WupT, hidden, basis_down, cdn, eidx, WdnT);

  phase3_kernel<<<(NTOK / 128) * (DMODEL / 128), 256, 0, stream>>>(
      hidden, WdnT, out, bias, eidx);
}

// Round 3
// 414.091 us; speedup vs baseline: 1.1095x; 1.0989x over previous
//
#include <hip/hip_runtime.h>
#include <cstdint>

#define NTOK 8192
#define DMODEL 1024
#define HDDIM 4096
#define NVEC 32

typedef float f32x4_v __attribute__((ext_vector_type(4)));
typedef __bf16 bf16x8 __attribute__((ext_vector_type(8)));
typedef unsigned short u16x4 __attribute__((ext_vector_type(4)));

__device__ __forceinline__ unsigned short f2bf(float f) {
  union { float f; uint32_t u; } x; x.f = f;
  uint32_t r = (x.u + 0x7FFFu + ((x.u >> 16) & 1u)) >> 16;
  return (unsigned short)r;
}

// tanh-form GELU via single v_exp_f32: x*sigmoid(2*sqrt(2/pi)*(x+0.044715x^3))
// |gelu_tanh - gelu_erf| <= ~5e-4 absolute -> negligible vs bf16 rounding.
__device__ __forceinline__ float gelu_fast(float x) {
  float t = x * x;
  float z = x * (2.3022137f + 0.1029431f * t);  // 2*sqrt(2/pi)*log2(e)*(1, 0.044715)
  float e = exp2f(-z);                           // v_exp_f32
  return x / (1.0f + e);
}

#define VMCNT(n) asm volatile("s_waitcnt vmcnt(" #n ")" ::: "memory")

__device__ __forceinline__ void gload16(const unsigned short* g, unsigned short* lds)
{
  __builtin_amdgcn_global_load_lds((__attribute__((address_space(1))) void*)g,
                                   (__attribute__((address_space(3))) void*)lds,
                                   16, 0, 0);
}

// ---------------------------------------------------------------------------
// Reconstruct + transpose body: outT[y][x] (bf16, ld=X) = sum_v c[v]*basis[v][x][y]
// 64x * 64y tile per block, 256 threads, LDS transpose. HBM-bound.
// ---------------------------------------------------------------------------
__device__ __forceinline__
void reconstruct_body(const float* __restrict__ basis,
                      const float* __restrict__ coeffs,
                      int e, unsigned short* __restrict__ outT,
                      int X, int Y, int tile, char* smem)
{
  float (*lds)[65] = (float (*)[65])smem;
  const int xtiles = X >> 6;
  const int bx = tile % xtiles;
  const int by = tile / xtiles;
  const int x0 = bx << 6, y0 = by << 6;
  const int t  = threadIdx.x;
  const int y4 = t & 15;
  const int xg = t >> 4;

  f32x4_v acc[4];
  #pragma unroll
  for (int i = 0; i < 4; ++i) acc[i] = (f32x4_v){0.f, 0.f, 0.f, 0.f};

  const size_t mat = (size_t)X * (size_t)Y;
  const float* base = basis + (size_t)(x0 + xg * 4) * Y + (y0 + y4 * 4);

  #pragma unroll 2
  for (int v = 0; v < NVEC; ++v) {
    const float cv = coeffs[e * NVEC + v];
    const float* pv = base + (size_t)v * mat;
    #pragma unroll
    for (int i = 0; i < 4; ++i) {
      f32x4_v d = *(const f32x4_v*)(pv + (size_t)i * Y);
      acc[i] += cv * d;
    }
  }

  #pragma unroll
  for (int i = 0; i < 4; ++i)
    #pragma unroll
    for (int j = 0; j < 4; ++j)
      lds[xg * 4 + i][y4 * 4 + j] = acc[i][j];
  __syncthreads();

  const int x4 = t & 15;
  const int yr = t >> 4;
  #pragma unroll
  for (int yy = 0; yy < 4; ++yy) {
    const int y = yr + yy * 16;
    u16x4 u;
    #pragma unroll
    for (int i = 0; i < 4; ++i) u[i] = f2bf(lds[x4 * 4 + i][y]);
    *(u16x4*)(outT + (size_t)(y0 + y) * X + x0 + x4 * 4) = u;
  }
}

// ---------------------------------------------------------------------------
// Phase 1: rec_up (blocks 0..1023) + cvt f32->bf16 grid-stride (blocks 1024..1535)
// ---------------------------------------------------------------------------
#define REC_UP_BLKS 1024   // (DMODEL/64)*(HDDIM/64)
#define CVT_BLKS    512

__global__ __launch_bounds__(256)
void phase1_kernel(const float* __restrict__ inputs,
                   const float* __restrict__ basis_up,
                   const float* __restrict__ cup,
                   const int* __restrict__ eidx_p,
                   unsigned short* __restrict__ A_bf,
                   unsigned short* __restrict__ WupT)
{
  __shared__ __align__(16) char smem[64 * 65 * 4];
  const int bid = blockIdx.x;
  if (bid < REC_UP_BLKS) {
    reconstruct_body(basis_up, cup, *eidx_p, WupT, DMODEL, HDDIM, bid, smem);
  } else {
    const int n4 = NTOK * DMODEL / 4;
    const int stride = CVT_BLKS * 256;
    for (int i = (bid - REC_UP_BLKS) * 256 + threadIdx.x; i < n4; i += stride) {
      f32x4_v v = ((const f32x4_v*)inputs)[i];
      u16x4 u;
      #pragma unroll
      for (int j = 0; j < 4; ++j) u[j] = f2bf(v[j]);
      ((u16x4*)A_bf)[i] = u;
    }
  }
}

// rec_dn standalone
__global__ __launch_bounds__(256)
void rec_kernel(const float* __restrict__ basis,
                const float* __restrict__ coeffs,
                const int* __restrict__ eidx_p,
                unsigned short* __restrict__ outT,
                int X, int Y)
{
  __shared__ __align__(16) char smem[64 * 65 * 4];
  reconstruct_body(basis, coeffs, *eidx_p, outT, X, Y, blockIdx.x, smem);
}

// ---------------------------------------------------------------------------
// 8-wave deep-pipelined GEMM: C[M,N] = A[M,K] * Bt[N,K]^T, bf16 in, fp32 acc.
// BK=32, 4-slot LDS ring (lead-3 prefetch, counted vmcnt), XOR chunk swizzle,
// 16x16x32 MFMA, waves 2M x 4N, per-phase {ds_read | stage | barrier | MFMA}.
// EPI==0: C = gelu(acc) -> bf16.  EPI==1: C = acc + bias[col] -> f32.
// ---------------------------------------------------------------------------
template<int BM, int BN, int EPI>
__global__ __launch_bounds__(512, 2)
void gemm8p(const unsigned short* __restrict__ A,
            const unsigned short* __restrict__ Bt,
            unsigned short* __restrict__ Cbf,
            float* __restrict__ Cf,
            const float* __restrict__ bias,
            const int* __restrict__ eidx_p,
            int M, int N, int K)
{
  constexpr int BK   = 32;
  constexpr int FM   = BM / 32;            // per-wave m-frags (WM=2)
  constexpr int FN   = BN / 64;            // per-wave n-frags (WN=4)
  constexpr int P    = (FM * FN) / 16;     // phases per K-tile (16 MFMA each)
  constexpr int SLOT = (BM + BN) * BK * 2; // bytes per ring slot (A then B)
  constexpr int L    = SLOT / 16 / 512;    // gloads / thread / K-tile
  constexpr int LPP  = L / P;              // gloads / thread / phase
  constexpr int ACH  = BM * 4;             // A 16B-chunks per slot

  __shared__ __align__(16) char smem[4 * SLOT];

  const int nb = N / BN;
  const int bm = blockIdx.x / nb, bn = blockIdx.x % nb;
  const int m0 = bm * BM, n0 = bn * BN;
  const int tid = threadIdx.x;
  const int w = tid >> 6, l = tid & 63;
  const int wm = w >> 2, wn = w & 3;
  const int lrow = l & 15, lkc = l >> 4;

  // stage source pointers (kt=0); LDS dest is linear (tid + j*512)*16.
  // swizzle: chunk c' in LDS holds global chunk c = c' ^ (row & 3)
  const unsigned short* src[L];
  #pragma unroll
  for (int j = 0; j < L; ++j) {
    const int q = tid + j * 512;
    if (q < ACH) {
      const int r = q >> 2, cs = (q & 3) ^ (r & 3);
      src[j] = A + (size_t)(m0 + r) * K + cs * 8;
    } else {
      const int q2 = q - ACH;
      const int r = q2 >> 2, cs = (q2 & 3) ^ (r & 3);
      src[j] = Bt + (size_t)(n0 + r) * K + cs * 8;
    }
  }

  // fragment read byte-offsets within a slot (swizzled)
  int aoff[FM], boff[FN];
  #pragma unroll
  for (int f = 0; f < FM; ++f) {
    const int r = wm * (BM / 2) + f * 16 + lrow;
    aoff[f] = r * 64 + ((lkc ^ (r & 3)) << 4);
  }
  #pragma unroll
  for (int n_ = 0; n_ < FN; ++n_) {
    const int r = wn * (BN / 4) + n_ * 16 + lrow;
    boff[n_] = BM * 64 + r * 64 + ((lkc ^ (r & 3)) << 4);
  }

  f32x4_v acc[FM][FN];
  #pragma unroll
  for (int f = 0; f < FM; ++f)
    #pragma unroll
    for (int n_ = 0; n_ < FN; ++n_) acc[f][n_] = (f32x4_v){0.f, 0.f, 0.f, 0.f};

  const int NT = K / BK;

  // prologue: stage tiles 0,1,2 into slots 0,1,2
  for (int tt = 0; tt < 3; ++tt) {
    char* sb = smem + tt * SLOT;
    #pragma unroll
    for (int j = 0; j < L; ++j)
      gload16(src[j] + tt * BK, (unsigned short*)(sb + (tid + j * 512) * 16));
  }
  if constexpr (L == 4) { VMCNT(8); } else { VMCNT(6); }  // tile 0 ready
  __builtin_amdgcn_s_barrier();
  __builtin_amdgcn_sched_barrier(0);

  bf16x8 bfr[FN];
  for (int t = 0; t < NT; ++t) {
    const char* sb = smem + (t & 3) * SLOT;
    char* pb = smem + ((t + 3) & 3) * SLOT;
    const bool do_stage = (t + 3 < NT);
    #pragma unroll
    for (int p = 0; p < P; ++p) {
      bf16x8 af[4];
      #pragma unroll
      for (int m_ = 0; m_ < 4; ++m_)
        af[m_] = *(const bf16x8*)(sb + aoff[p * 4 + m_]);
      if (p == 0) {
        #pragma unroll
        for (int n_ = 0; n_ < FN; ++n_)
          bfr[n_] = *(const bf16x8*)(sb + boff[n_]);
      }
      if (do_stage) {
        #pragma unroll
        for (int jj = 0; jj < LPP; ++jj) {
          const int j = p * LPP + jj;
          gload16(src[j] + (t + 3) * BK, (unsigned short*)(pb + (tid + j * 512) * 16));
        }
      }
      __builtin_amdgcn_s_barrier();
      __builtin_amdgcn_s_setprio(1);
      #pragma unroll
      for (int m_ = 0; m_ < 4; ++m_)
        #pragma unroll
        for (int n_ = 0; n_ < FN; ++n_)
          acc[p * 4 + m_][n_] = __builtin_amdgcn_mfma_f32_16x16x32_bf16(
              af[m_], bfr[n_], acc[p * 4 + m_][n_], 0, 0, 0);
      __builtin_amdgcn_s_setprio(0);
      if (p == P - 1) {
        // wait for tile t+1 (FIFO: leaves later tiles' loads in flight)
        if (t < NT - 3)       { if constexpr (L == 4) { VMCNT(8); } else { VMCNT(6); } }
        else if (t == NT - 3) { if constexpr (L == 4) { VMCNT(4); } else { VMCNT(3); } }
        else if (t == NT - 2) { VMCNT(0); }
      }
      __builtin_amdgcn_s_barrier();
      __builtin_amdgcn_sched_barrier(0);
    }
  }

  // epilogue. C/D frag: col = lane&15, row = (lane>>4)*4 + reg
  const int colq = l & 15;
  const int rowq = (l >> 4) * 4;
  if constexpr (EPI == 0) {
    #pragma unroll
    for (int f = 0; f < FM; ++f)
      #pragma unroll
      for (int n_ = 0; n_ < FN; ++n_) {
        const int col = n0 + wn * (BN / 4) + n_ * 16 + colq;
        #pragma unroll
        for (int r = 0; r < 4; ++r) {
          const int row = m0 + wm * (BM / 2) + f * 16 + rowq + r;
          Cbf[(size_t)row * N + col] = f2bf(gelu_fast(acc[f][n_][r]));
        }
      }
  } else {
    const int e = *eidx_p;
    const float* brow = bias + (size_t)e * N;
    #pragma unroll
    for (int n_ = 0; n_ < FN; ++n_) {
      const int col = n0 + wn * (BN / 4) + n_ * 16 + colq;
      const float bv = brow[col];
      #pragma unroll
      for (int f = 0; f < FM; ++f)
        #pragma unroll
        for (int r = 0; r < 4; ++r) {
          const int row = m0 + wm * (BM / 2) + f * 16 + rowq + r;
          Cf[(size_t)row * N + col] = acc[f][n_][r] + bv;
        }
    }
  }
}

// ---------------------------------------------------------------------------
extern "C" void kernel_launch(void* const* d_in, const int* in_sizes, int n_in,
                              void* d_out, int out_size, void* d_ws, size_t ws_size,
                              hipStream_t stream)
{
  const float* inputs     = (const float*)d_in[0];
  const float* basis_up   = (const float*)d_in[1];
  const float* basis_down = (const float*)d_in[2];
  const float* cup        = (const float*)d_in[3];
  const float* cdn        = (const float*)d_in[4];
  const float* bias       = (const float*)d_in[5];
  const int*   eidx       = (const int*)d_in[6];
  float*       out        = (float*)d_out;

  char* ws = (char*)d_ws;
  unsigned short* A_bf   = (unsigned short*)(ws);                  // 16 MB
  unsigned short* WupT   = (unsigned short*)(ws + (16u << 20));    //  8 MB  [HDDIM][DMODEL]
  unsigned short* WdnT   = (unsigned short*)(ws + (24u << 20));    //  8 MB  [DMODEL][HDDIM]
  unsigned short* hidden = (unsigned short*)(ws + (32u << 20));    // 64 MB  [NTOK][HDDIM]

  // rec_up + cvt (both HBM-bound, concurrent)
  phase1_kernel<<<REC_UP_BLKS + CVT_BLKS, 256, 0, stream>>>(
      inputs, basis_up, cup, eidx, A_bf, WupT);

  // W_downT[d][h] = sum_v c[v]*basis_down[v][h][d]
  rec_kernel<<<(HDDIM / 64) * (DMODEL / 64), 256, 0, stream>>>(
      basis_down, cdn, eidx, WdnT, HDDIM, DMODEL);

  // hidden = gelu(A_bf @ WupT^T)   M=8192 N=4096 K=1024  (512 blocks)
  gemm8p<256, 256, 0><<<(NTOK / 256) * (HDDIM / 256), 512, 0, stream>>>(
      A_bf, WupT, hidden, nullptr, nullptr, nullptr, NTOK, HDDIM, DMODEL);

  // out = hidden @ WdnT^T + bias   M=8192 N=1024 K=4096  (256 blocks)
  gemm8p<128, 256, 1><<<(NTOK / 128) * (DMODEL / 256), 512, 0, stream>>>(
      hidden, WdnT, nullptr, out, bias, eidx, NTOK, DMODEL, HDDIM);
}